// Round 7
// baseline (62.897 us; speedup 1.0000x reference)
//
#include <hip/hip_runtime.h>
#include <hip/hip_fp16.h>

#define WALK_LEN 40
#define WINDOW   5
#define NPAIRS   370
#define BATCHSZ  512
#define NEGK     5
#define NPOS     (BATCHSZ * NPAIRS)        // 189440
#define EMB      128
#define NQ       (BATCHSZ * WALK_LEN)      // 20480 flat-walk rows
#define THREADS  512
#define GROUPS   (THREADS / 8)             // 64 8-lane groups
#define PPB      124                       // pairs per block (3 blocks/batch)
#define NBLOCKS  (BATCHSZ * 3)             // 1536

struct PairTab { short src[NPAIRS]; short dst[NPAIRS]; };

constexpr PairTab make_pairs() {
    PairTab t{};
    int k = 0;
    for (int i = 0; i < WALK_LEN; ++i) {
        int lo = (i - WINDOW > 0) ? (i - WINDOW) : 0;
        for (int j = lo; j < i; ++j) { t.src[k] = (short)j; t.dst[k] = (short)i; ++k; }
        int hi = (i + 1 + WINDOW < WALK_LEN) ? (i + 1 + WINDOW) : WALK_LEN;
        for (int j = i + 1; j < hi; ++j) { t.src[k] = (short)j; t.dst[k] = (short)i; ++k; }
    }
    return t;
}

__constant__ PairTab g_pairs = make_pairs();

// f16 bits -> e5m2 (top 8 bits of fp16, round-to-nearest-even)
__device__ __forceinline__ unsigned char e5m2_from_h(unsigned short u) {
    return (unsigned char)((u + 0x7Fu + ((u >> 8) & 1u)) >> 8);
}

// ---- phase 1: gather the 20480 flat-walk rows into dense fp16 (node+ctx),
// plus a PERMUTED e5m2 copy of ctx for the 128B-per-row neg gather. ----
// Permutation: dense-fp8 row byte (16*l + t), l=0..7, t=0..15 holds element
//   e = (t<8) ? 8l+t : 64 + 8l + (t-8)
// so that lane l's single uint4 aligns with the fp16 LDS fragment layout
// (lane l owns elems [8l..8l+7] and [64+8l..64+8l+7]).
__global__ __launch_bounds__(256) void dw_gather(
    const int*   __restrict__ walk,
    const float* __restrict__ nodeE,
    const float* __restrict__ ctxE,
    unsigned short* __restrict__ dN,    // [NQ*EMB] fp16
    unsigned short* __restrict__ dC,    // [NQ*EMB] fp16
    unsigned char*  __restrict__ dC8)   // [NQ*128] e5m2 permuted
{
    int idx = blockIdx.x * 256 + threadIdx.x;      // 0 .. 2*NQ*32-1
    const int is_ctx = (idx >= NQ * 32);
    if (is_ctx) idx -= NQ * 32;
    const int q = idx >> 5, c = idx & 31;          // thread owns elems 4c..4c+3
    const int row = walk[q];
    const float* src = (is_ctx ? ctxE : nodeE) + (size_t)row * EMB;
    const float4 v = *((const float4*)src + c);

    const __half h0 = __float2half(v.x), h1 = __float2half(v.y);
    const __half h2 = __float2half(v.z), h3 = __float2half(v.w);
    ushort4 o;
    o.x = __half_as_ushort(h0); o.y = __half_as_ushort(h1);
    o.z = __half_as_ushort(h2); o.w = __half_as_ushort(h3);
    unsigned short* dst = (is_ctx ? dC : dN) + (size_t)q * EMB;
    *((ushort4*)dst + c) = o;

    if (is_ctx) {
        uchar4 e;
        e.x = e5m2_from_h(o.x); e.y = e5m2_from_h(o.y);
        e.z = e5m2_from_h(o.z); e.w = e5m2_from_h(o.w);
        const int off = (c < 16) ? ((c >> 1) * 16 + (c & 1) * 4)
                                 : (((c - 16) >> 1) * 16 + 8 + (c & 1) * 4);
        *((uchar4*)(dC8 + (size_t)q * 128 + off)) = e;
    }
}

// decode one uint (4 e5m2 bytes) into two half2s (elems in ascending order)
#define E5M2_DECODE(u, h2a, h2b)                                            \
    do {                                                                    \
        unsigned _t0 = ((u & 0xffu) << 8) | ((u & 0xff00u) << 16);          \
        unsigned _t1 = ((u >> 8) & 0xff00u) | (u & 0xff000000u);            \
        h2a = *(__half2*)&_t0; h2b = *(__half2*)&_t1;                       \
    } while (0)

// hfma2-dot of a uint4 (8 fp16) against another uint4 (8 fp16)
#define H2_DOT4(acch, A, C)                                                 \
    do {                                                                    \
        const __half2* _a = (const __half2*)&(A);                           \
        const __half2* _c = (const __half2*)&(C);                           \
        acch = __hfma2(_a[0], _c[0], acch); acch = __hfma2(_a[1], _c[1], acch); \
        acch = __hfma2(_a[2], _c[2], acch); acch = __hfma2(_a[3], _c[3], acch); \
    } while (0)

// ---- phase 2: one block = 1/3 batch (<=124 pairs) ----
__global__ __launch_bounds__(THREADS) void dw_score(
    const int* __restrict__ negdst,                 // [NPOS*NEGK] -> dense row id
    const unsigned short* __restrict__ dN,
    const unsigned short* __restrict__ dC,
    const unsigned char*  __restrict__ dC8,
    float* __restrict__ out)
{
    __shared__ __align__(16) unsigned int sN[WALK_LEN * 64];   // fp16 rows, 10 KB
    __shared__ __align__(16) unsigned int sC[WALK_LEN * 64];   // 10 KB
    __shared__ float wsum[THREADS / 64];

    const int b   = blockIdx.x / 3;
    const int seg = blockIdx.x % 3;
    const int tid = threadIdx.x;

    // stage batch's 40+40 fp16 rows from CONTIGUOUS dense memory
    {
        const uint4* srcN = (const uint4*)(dN + (size_t)b * WALK_LEN * EMB);
        const uint4* srcC = (const uint4*)(dC + (size_t)b * WALK_LEN * EMB);
        for (int u = tid; u < WALK_LEN * 16; u += THREADS) {
            ((uint4*)sN)[u] = srcN[u];
            ((uint4*)sC)[u] = srcC[u];
        }
    }
    __syncthreads();

    const int lane8 = tid & 7;
    const int grp   = tid >> 3;           // 0..63
    const int jbase = seg * PPB;
    float acc = 0.0f;

    #pragma unroll 1
    for (int it = 0; it < 2; ++it) {
        const int jj = it * GROUPS + grp;            // 0..127
        const int j  = jbase + jj;
        if (jj < PPB && j < NPAIRS) {
            const int p  = b * NPAIRS + j;
            const int sj = g_pairs.src[j];
            const int dj = g_pairs.dst[j];

            const int* nb = negdst + p * NEGK;
            const int q0 = nb[0], q1 = nb[1], q2 = nb[2], q3 = nb[3], q4 = nb[4];

            // 5 neg rows: ONE uint4 load (128B segment) per row per group
            const uint4 x0 = *((const uint4*)(dC8 + (size_t)q0 * 128) + lane8);
            const uint4 x1 = *((const uint4*)(dC8 + (size_t)q1 * 128) + lane8);
            const uint4 x2 = *((const uint4*)(dC8 + (size_t)q2 * 128) + lane8);
            const uint4 x3 = *((const uint4*)(dC8 + (size_t)q3 * 128) + lane8);
            const uint4 x4 = *((const uint4*)(dC8 + (size_t)q4 * 128) + lane8);

            // LDS fp16 fragments: lane l owns elems [8l..8l+7], [64+8l..64+8l+7]
            const uint4* rA = (const uint4*)(sN + sj * 64);
            const uint4* rC = (const uint4*)(sC + dj * 64);
            const uint4* rS = (const uint4*)(sN + dj * 64);
            const uint4 a0 = rA[lane8], a1 = rA[lane8 + 8];
            const uint4 c0 = rC[lane8], c1 = rC[lane8 + 8];
            const uint4 n0 = rS[lane8], n1 = rS[lane8 + 8];

            // ---- positive (packed fp16 dot) ----
            {
                __half2 hd = __float2half2_rn(0.f);
                H2_DOT4(hd, a0, c0);
                H2_DOT4(hd, a1, c1);
                float d = __low2float(hd) + __high2float(hd);
                d += __shfl_xor(d, 1); d += __shfl_xor(d, 2); d += __shfl_xor(d, 4);
                const float s = fminf(6.f, fmaxf(-6.f, d));
                acc += log1pf(__expf(-s));
            }

            // ---- negatives: decode x (permuted e5m2) -> 8 half2 aligned with n ----
            #define NEG_TERM(X)                                                   \
            do {                                                                  \
                const unsigned* _u = (const unsigned*)&(X);                       \
                __half2 p0, p1, p2, p3, p4, p5, p6, p7;                           \
                E5M2_DECODE(_u[0], p0, p1);   /* elems 8l+0..3   <-> n0 h2 0,1 */ \
                E5M2_DECODE(_u[1], p2, p3);   /* elems 8l+4..7   <-> n0 h2 2,3 */ \
                E5M2_DECODE(_u[2], p4, p5);   /* elems 64+8l+0..3<-> n1 h2 0,1 */ \
                E5M2_DECODE(_u[3], p6, p7);   /* elems 64+8l+4..7<-> n1 h2 2,3 */ \
                const __half2* _n0 = (const __half2*)&n0;                         \
                const __half2* _n1 = (const __half2*)&n1;                         \
                __half2 hd = __float2half2_rn(0.f);                               \
                hd = __hfma2(p0, _n0[0], hd); hd = __hfma2(p1, _n0[1], hd);       \
                hd = __hfma2(p2, _n0[2], hd); hd = __hfma2(p3, _n0[3], hd);       \
                hd = __hfma2(p4, _n1[0], hd); hd = __hfma2(p5, _n1[1], hd);       \
                hd = __hfma2(p6, _n1[2], hd); hd = __hfma2(p7, _n1[3], hd);       \
                float d = __low2float(hd) + __high2float(hd);                     \
                d += __shfl_xor(d, 1); d += __shfl_xor(d, 2); d += __shfl_xor(d, 4);\
                const float s = fminf(6.f, fmaxf(-6.f, d));                       \
                acc += log1pf(__expf(s));                                         \
            } while (0)
            NEG_TERM(x0);
            NEG_TERM(x1);
            NEG_TERM(x2);
            NEG_TERM(x3);
            NEG_TERM(x4);
            #undef NEG_TERM
        }
    }

    // group sums -> wave sum (each group counted once)
    acc += __shfl_xor(acc, 8);
    acc += __shfl_xor(acc, 16);
    acc += __shfl_xor(acc, 32);

    if ((tid & 63) == 0) wsum[tid >> 6] = acc;
    __syncthreads();
    if (tid == 0) {
        float tot = 0.f;
        #pragma unroll
        for (int w = 0; w < THREADS / 64; ++w) tot += wsum[w];
        atomicAdd(out, tot * (1.0f / (float)NPOS));
    }
}

extern "C" void kernel_launch(void* const* d_in, const int* in_sizes, int n_in,
                              void* d_out, int out_size, void* d_ws, size_t ws_size,
                              hipStream_t stream) {
    const int*   walk   = (const int*)d_in[0];
    const int*   negdst = (const int*)d_in[1];
    const float* nodeE  = (const float*)d_in[2];
    const float* ctxE   = (const float*)d_in[3];
    float*       out    = (float*)d_out;

    unsigned short* dN  = (unsigned short*)d_ws;
    unsigned short* dC  = dN + (size_t)NQ * EMB;
    unsigned char*  dC8 = (unsigned char*)(dC + (size_t)NQ * EMB);

    hipMemsetAsync(out, 0, sizeof(float), stream);
    dw_gather<<<(2 * NQ * 32) / 256, 256, 0, stream>>>(walk, nodeE, ctxE, dN, dC, dC8);
    dw_score<<<NBLOCKS, THREADS, 0, stream>>>(negdst, dN, dC, dC8, out);
}